// Round 7
// baseline (297.176 us; speedup 1.0000x reference)
//
#include <hip/hip_runtime.h>
#include <cstdint>
#include <cstddef>

static constexpr int B_ = 2, S_ = 2048, D_ = 1024, H_ = 16, HD_ = 64;

typedef float f32x4 __attribute__((ext_vector_type(4)));
typedef short bf16x8 __attribute__((ext_vector_type(8)));

__device__ __forceinline__ unsigned short f2bf(float f) {
    union { float f; unsigned int u; } v; v.f = f;
    unsigned int r = v.u + 0x7FFFu + ((v.u >> 16) & 1u);   // RNE
    return (unsigned short)(r >> 16);
}
__device__ __forceinline__ float bf2f(unsigned short h) {
    union { unsigned int u; float f; } v; v.u = ((unsigned int)h) << 16;
    return v.f;
}

__device__ __forceinline__ unsigned pack2bf(float a, float b) {
#if __has_builtin(__builtin_amdgcn_cvt_pk_bf16_f32)
    auto p = __builtin_amdgcn_cvt_pk_bf16_f32(a, b);
    unsigned u; __builtin_memcpy(&u, &p, 4);
    return u;
#else
    return (unsigned)f2bf(a) | ((unsigned)f2bf(b) << 16);
#endif
}

// byte r of u -> float (0.0 or 1.0 for our inverted mask bytes)
__device__ __forceinline__ float ubyte2f(unsigned u, int r) {
#if __has_builtin(__builtin_amdgcn_cvt_f32_ubyte0)
    switch (r) {
        case 0: return __builtin_amdgcn_cvt_f32_ubyte0(u);
        case 1: return __builtin_amdgcn_cvt_f32_ubyte1(u);
        case 2: return __builtin_amdgcn_cvt_f32_ubyte2(u);
        default: return __builtin_amdgcn_cvt_f32_ubyte3(u);
    }
#else
    return (float)((u >> (8 * r)) & 0xFFu);
#endif
}

// async global->LDS, 16B per lane. LDS dest = wave-uniform base + lane*16.
__device__ __forceinline__ void gload_lds16(const void* g, void* l) {
    __builtin_amdgcn_global_load_lds(
        (const __attribute__((address_space(1))) void*)g,
        (__attribute__((address_space(3))) void*)l, 16, 0, 0);
}

// ---------------------------------------------------------------------------
// Fused prep: [0,2048) cast x->bf16 | [2048,4096) mask int32 -> INVERTED u8
// (1 = keep, 0 = masked) | [4096,4864) W transpose+cast.
// ---------------------------------------------------------------------------
__global__ __launch_bounds__(256)
void prep(const float* __restrict__ x, unsigned short* __restrict__ xo,
          const int* __restrict__ m, unsigned char* __restrict__ mo,
          const float* __restrict__ Wq, const float* __restrict__ Wk,
          const float* __restrict__ Wv, unsigned short* __restrict__ wt) {
    __shared__ unsigned short Ts[64][72];
    const int bid = blockIdx.x, t = threadIdx.x;
    if (bid < 2048) {
        size_t i = ((size_t)bid * 256 + t) * 8;
        float4 a = *(const float4*)(x + i);
        float4 c = *(const float4*)(x + i + 4);
        uint4 r;
        r.x = pack2bf(a.x, a.y); r.y = pack2bf(a.z, a.w);
        r.z = pack2bf(c.x, c.y); r.w = pack2bf(c.z, c.w);
        *(uint4*)(xo + i) = r;
    } else if (bid < 4096) {
        size_t i = ((size_t)(bid - 2048) * 256 + t) * 16;
        uint4 r;
        unsigned w[4];
        #pragma unroll
        for (int g = 0; g < 4; ++g) {
            int4 v = *(const int4*)(m + i + g * 4);
            w[g] = (v.x ? 0u : 1u) | (v.y ? 0u : 1u << 8) |
                   (v.z ? 0u : 1u << 16) | (v.w ? 0u : 1u << 24);
        }
        r.x = w[0]; r.y = w[1]; r.z = w[2]; r.w = w[3];
        *(uint4*)(mo + i) = r;
    } else {
        const int tid = bid - 4096;            // 0..767
        const int mat = tid >> 8, tile = tid & 255;
        const float* __restrict__ W = (mat == 0) ? Wq : (mat == 1) ? Wk : Wv;
        unsigned short* __restrict__ o = wt + (size_t)mat * D_ * D_;
        const int n0 = (tile & 15) * 64, k0 = (tile >> 4) * 64;
        {
            const int nl = t & 63, kb = t >> 6;
            #pragma unroll
            for (int i = 0; i < 16; ++i) {
                int k = kb + i * 4;
                Ts[nl][k] = f2bf(W[(size_t)(k0 + k) * D_ + n0 + nl]);
            }
        }
        __syncthreads();
        {
            const int kl = t & 63, nb = t >> 6;
            #pragma unroll
            for (int i = 0; i < 16; ++i) {
                int n = nb + i * 4;
                o[(size_t)(n0 + n) * D_ + k0 + kl] = Ts[n][kl];
            }
        }
    }
}

// ---------------------------------------------------------------------------
// QKV GEMM, bf16 MFMA 16x16x32. 128x128 tile, BK=32, single-barrier dbuf DMA,
// XOR-swizzled LDS (unchanged from round 5 — verified passing).
// mat0 (Q): scaled by 0.125*log2(e). mat2 (V): stored transposed vt[bh][d][s].
// ---------------------------------------------------------------------------
__global__ __launch_bounds__(256)
void qkv_gemm(const unsigned short* __restrict__ xb, const unsigned short* __restrict__ wt,
              const float* __restrict__ bq, const float* __restrict__ bk,
              const float* __restrict__ bv,
              unsigned short* __restrict__ qo, unsigned short* __restrict__ ko,
              unsigned short* __restrict__ vto) {
    const int bx = blockIdx.x;
    const int by = blockIdx.y;
    const int mat = bx >> 3;
    const int ncol0 = (bx & 7) * 128;
    const float* __restrict__ bias = (mat == 0) ? bq : (mat == 1) ? bk : bv;
    const unsigned short* __restrict__ Wm = wt + (size_t)mat * D_ * D_;

    __shared__ unsigned short As[2][128 * 32];
    __shared__ unsigned short Bs[2][128 * 32];

    const int t = threadIdx.x;
    const int w = t >> 6, lane = t & 63;
    const int l15 = lane & 15, quad = lane >> 4;
    const int mw = (w >> 1) * 64, nw = (w & 1) * 64;
    const int rowBase = by * 128;

    const int r16 = lane >> 2;
    const int sslot = lane & 3;
    const int sg = (sslot ^ ((r16 >> 1) & 3)) * 8;
    const int rcol = (quad ^ ((l15 >> 1) & 3)) * 8;

    f32x4 acc[4][4] = {};

    #pragma unroll
    for (int j = 0; j < 2; ++j) {
        const int r0 = w * 32 + j * 16;
        gload_lds16(xb + (size_t)(rowBase + r0 + r16) * D_ + sg, &As[0][r0 * 32]);
        gload_lds16(Wm + (size_t)(ncol0 + r0 + r16) * D_ + sg, &Bs[0][r0 * 32]);
    }

    for (int it = 0; it < 32; ++it) {
        const int cur = it & 1;
        __syncthreads();
        if (it + 1 < 32) {
            const int ktn = (it + 1) * 32;
            #pragma unroll
            for (int j = 0; j < 2; ++j) {
                const int r0 = w * 32 + j * 16;
                gload_lds16(xb + (size_t)(rowBase + r0 + r16) * D_ + ktn + sg,
                            &As[cur ^ 1][r0 * 32]);
                gload_lds16(Wm + (size_t)(ncol0 + r0 + r16) * D_ + ktn + sg,
                            &Bs[cur ^ 1][r0 * 32]);
            }
        }

        bf16x8 a[4], b[4];
        #pragma unroll
        for (int i = 0; i < 4; ++i)
            a[i] = *(const bf16x8*)&As[cur][(mw + i * 16 + l15) * 32 + rcol];
        #pragma unroll
        for (int j = 0; j < 4; ++j)
            b[j] = *(const bf16x8*)&Bs[cur][(nw + j * 16 + l15) * 32 + rcol];
        #pragma unroll
        for (int i = 0; i < 4; ++i)
            #pragma unroll
            for (int j = 0; j < 4; ++j)
                acc[i][j] = __builtin_amdgcn_mfma_f32_16x16x32_bf16(a[i], b[j], acc[i][j], 0, 0, 0);
    }

    if (mat < 2) {
        unsigned short* __restrict__ O = (mat == 0) ? qo : ko;
        const float osc = (mat == 0) ? 0.18033688011112443f : 1.0f;  // 0.125*log2(e)
        #pragma unroll
        for (int j = 0; j < 4; ++j) {
            const int col = ncol0 + nw + j * 16 + l15;
            const float bb = bias[col];
            #pragma unroll
            for (int i = 0; i < 4; ++i)
                #pragma unroll
                for (int r = 0; r < 4; ++r) {
                    const int m = rowBase + mw + i * 16 + quad * 4 + r;
                    O[(size_t)m * D_ + col] = f2bf((acc[i][j][r] + bb) * osc);
                }
        }
    } else {
        #pragma unroll
        for (int j = 0; j < 4; ++j) {
            const int col = ncol0 + nw + j * 16 + l15;
            const float bb = bias[col];
            const int hh = col >> 6, hd = col & 63;
            #pragma unroll
            for (int i = 0; i < 4; ++i) {
                const int m0 = rowBase + mw + i * 16 + quad * 4;
                const int bg = m0 >> 11, s0 = m0 & 2047;
                ushort4 pk;
                pk.x = f2bf(acc[i][j][0] + bb);
                pk.y = f2bf(acc[i][j][1] + bb);
                pk.z = f2bf(acc[i][j][2] + bb);
                pk.w = f2bf(acc[i][j][3] + bb);
                *(ushort4*)&vto[(((size_t)bg * H_ + hh) * HD_ + hd) * S_ + s0] = pk;
            }
        }
    }
}

// ---------------------------------------------------------------------------
// Flash attention, bf16 MFMA, S^T orientation, 2-way KV-split.
// Block = (qt, h, b*2+half); processes keys [half*1024, half*1024+1024).
// Emits UNNORMALIZED partial O (half0: bf16 -> O0ws; half1: fp32 -> d_out)
// and row-sum l; combine() normalizes.
//   K: LDS double-buffered DMA, XOR-swizzled (granule ^ row&7).
//   V: read directly from global vt[bh][d][s] (L2-resident slice) as B-frags.
//   P: LDS [128][64] unpadded, element (qr,k) at qr*64+((k>>3)^(qr&7))*8+(k&7).
// Masking: p = exp2(score * fm), fm = inverted mask byte (0 or 1)
//   -> masked gives exp2(0)=1 (reference quirk). Q pre-scaled by 0.125*log2e.
// LDS total 32 KB.
// ---------------------------------------------------------------------------
__global__ __launch_bounds__(256)
void attn_mfma(const unsigned short* __restrict__ qmat,
               const unsigned short* __restrict__ kmat,
               const unsigned short* __restrict__ vtg,
               const unsigned char* __restrict__ msk,
               unsigned short* __restrict__ O0, float* __restrict__ O1,
               float* __restrict__ lws) {
    const int qt = blockIdx.x, h = blockIdx.y;
    const int b = blockIdx.z >> 1, half = blockIdx.z & 1;
    const int t = threadIdx.x, w = t >> 6, lane = t & 63;
    const int l15 = lane & 15, quad = lane >> 4;
    const int q0 = qt * 128;
    const int kb0 = half * 1024;

    __shared__ unsigned short Ks[2][64 * 64];   // [key][d] swizzled
    __shared__ unsigned short Ps[128 * 64];     // [qrow][key] swizzled

    const size_t bh = (size_t)b * S_ * D_ + (size_t)h * HD_;
    const unsigned short* __restrict__ qp = qmat + bh;
    const unsigned short* __restrict__ kp = kmat + bh;
    const unsigned short* __restrict__ vp = vtg + ((size_t)b * H_ + h) * HD_ * S_;
    const unsigned char* __restrict__ mb = msk + (size_t)b * S_ * S_;

    const int rs = lane >> 3, sslot = lane & 7;
    const int sg = (sslot ^ rs) * 8;            // staged global granule (shorts)
    const int l7 = l15 & 7;

    // Q fragments in registers (loop-invariant)
    bf16x8 qfr[2][2];
    #pragma unroll
    for (int nt = 0; nt < 2; ++nt)
        #pragma unroll
        for (int kst = 0; kst < 2; ++kst)
            qfr[nt][kst] = *(const bf16x8*)(qp +
                (size_t)(q0 + w * 32 + nt * 16 + l15) * D_ + kst * 32 + quad * 8);

    f32x4 accO[2][4] = {};
    f32x4 lsA[2] = {};
    bf16x8 ones;
    #pragma unroll
    for (int i = 0; i < 8; ++i) ones[i] = (short)0x3F80;   // bf16 1.0

    // prologue: stage K tile 0 into buffer 0
    #pragma unroll
    for (int j = 0; j < 2; ++j) {
        const int rb = w * 16 + j * 8;
        gload_lds16(kp + (size_t)(kb0 + rb + rs) * D_ + sg, &Ks[0][rb * 64]);
    }

    for (int it = 0; it < 16; ++it) {
        const int cur = it & 1;
        const int kt = kb0 + it * 64;
        __syncthreads();   // buf cur DMA drained; readers of buf cur^1 done

        // 1) mask loads (inverted bytes: 1=keep, 0=masked)
        unsigned mu[2][4];
        #pragma unroll
        for (int nt = 0; nt < 2; ++nt) {
            const int qr = w * 32 + nt * 16 + l15;
            const unsigned char* __restrict__ mrow = mb + (size_t)(q0 + qr) * S_ + kt;
            #pragma unroll
            for (int mt = 0; mt < 4; ++mt)
                mu[nt][mt] = *(const unsigned*)(mrow + mt * 16 + quad * 4);
        }

        // 2) prefetch next K tile
        if (it + 1 < 16) {
            const int ktn = kt + 64;
            #pragma unroll
            for (int j = 0; j < 2; ++j) {
                const int rb = w * 16 + j * 8;
                gload_lds16(kp + (size_t)(ktn + rb + rs) * D_ + sg, &Ks[cur ^ 1][rb * 64]);
            }
        }

        // 3) S^T = K·Q^T
        f32x4 sc[4][2] = {};
        #pragma unroll
        for (int kst = 0; kst < 2; ++kst) {
            bf16x8 kfr[4];
            #pragma unroll
            for (int mt = 0; mt < 4; ++mt) {
                const int R = mt * 16 + l15;
                kfr[mt] = *(const bf16x8*)&Ks[cur][R * 64 + ((kst * 4 + quad) ^ l7) * 8];
            }
            #pragma unroll
            for (int mt = 0; mt < 4; ++mt)
                #pragma unroll
                for (int nt = 0; nt < 2; ++nt)
                    sc[mt][nt] = __builtin_amdgcn_mfma_f32_16x16x32_bf16(kfr[mt], qfr[nt][kst], sc[mt][nt], 0, 0, 0);
        }

        // 4) p = exp2(s * fm); packed P^T store into swizzled Ps.
        //    Keys written: k = mt*16 + quad*4 + r  (granule mt*2+(quad>>1),
        //    intra-granule offset (quad&1)*4).
        #pragma unroll
        for (int nt = 0; nt < 2; ++nt) {
            const int qr = w * 32 + nt * 16 + l15;
            #pragma unroll
            for (int mt = 0; mt < 4; ++mt) {
                float p[4];
                #pragma unroll
                for (int r = 0; r < 4; ++r) {
                    float fm = ubyte2f(mu[nt][mt], r);
                    p[r] = __builtin_amdgcn_exp2f(sc[mt][nt][r] * fm);
                }
                uint2 pk;
                pk.x = pack2bf(p[0], p[1]);
                pk.y = pack2bf(p[2], p[3]);
                const int gw = (mt * 2 + (quad >> 1)) ^ l7;     // granule swizzle
                *(uint2*)&Ps[qr * 64 + gw * 8 + (quad & 1) * 4] = pk;
            }
        }
        // Ps rows are wave-private (w*32 strip): no barrier needed.

        // 5) O += P·V (V B-frags from global), lsum += P·1
        #pragma unroll
        for (int kst = 0; kst < 2; ++kst) {
            bf16x8 vfr[4];
            #pragma unroll
            for (int dt = 0; dt < 4; ++dt)
                vfr[dt] = *(const bf16x8*)(vp + (size_t)(dt * 16 + l15) * S_ + kt + kst * 32 + quad * 8);
            #pragma unroll
            for (int mt = 0; mt < 2; ++mt) {
                const int R = w * 32 + mt * 16 + l15;
                bf16x8 pfr = *(const bf16x8*)&Ps[R * 64 + ((kst * 4 + quad) ^ l7) * 8];
                #pragma unroll
                for (int dt = 0; dt < 4; ++dt)
                    accO[mt][dt] = __builtin_amdgcn_mfma_f32_16x16x32_bf16(pfr, vfr[dt], accO[mt][dt], 0, 0, 0);
                lsA[mt] = __builtin_amdgcn_mfma_f32_16x16x32_bf16(pfr, ones, lsA[mt], 0, 0, 0);
            }
        }
    }

    // store UNNORMALIZED partial O + l
    float* __restrict__ lp = lws + (((size_t)half * B_ + b) * H_ + h) * S_ + q0;
    if (half == 0) {
        unsigned short* __restrict__ ob = O0 + ((size_t)b * S_ + q0) * D_ + (size_t)h * HD_;
        #pragma unroll
        for (int mt = 0; mt < 2; ++mt)
            #pragma unroll
            for (int r = 0; r < 4; ++r) {
                const int qr = w * 32 + mt * 16 + quad * 4 + r;
                if (l15 == 0) lp[qr] = lsA[mt][r];
                #pragma unroll
                for (int dt = 0; dt < 4; ++dt)
                    ob[(size_t)qr * D_ + dt * 16 + l15] = f2bf(accO[mt][dt][r]);
            }
    } else {
        float* __restrict__ ob = O1 + ((size_t)b * S_ + q0) * D_ + (size_t)h * HD_;
        #pragma unroll
        for (int mt = 0; mt < 2; ++mt)
            #pragma unroll
            for (int r = 0; r < 4; ++r) {
                const int qr = w * 32 + mt * 16 + quad * 4 + r;
                if (l15 == 0) lp[qr] = lsA[mt][r];
                #pragma unroll
                for (int dt = 0; dt < 4; ++dt)
                    ob[(size_t)qr * D_ + dt * 16 + l15] = accO[mt][dt][r];
            }
    }
}

// ---------------------------------------------------------------------------
// combine: out = (bf2f(O0) + O1) / (l0 + l1).  O1 lives in d_out (in-place).
// ---------------------------------------------------------------------------
__global__ __launch_bounds__(256)
void combine(const unsigned short* __restrict__ O0, float* __restrict__ out,
             const float* __restrict__ lws) {
    const size_t i = ((size_t)blockIdx.x * 256 + threadIdx.x) * 4;
    const int sf = (int)(i >> 10);           // row in [0, B*S)
    const int b = sf >> 11, s = sf & 2047;
    const int h = ((int)i & 1023) >> 6;
    const float l0 = lws[(((size_t)0 * B_ + b) * H_ + h) * S_ + s];
    const float l1 = lws[(((size_t)1 * B_ + b) * H_ + h) * S_ + s];
    const float inv = 1.0f / (l0 + l1);
    ushort4 a = *(const ushort4*)(O0 + i);
    float4 c = *(const float4*)(out + i);
    float4 r;
    r.x = (bf2f(a.x) + c.x) * inv; r.y = (bf2f(a.y) + c.y) * inv;
    r.z = (bf2f(a.z) + c.z) * inv; r.w = (bf2f(a.w) + c.w) * inv;
    *(float4*)(out + i) = r;
}

extern "C" void kernel_launch(void* const* d_in, const int* in_sizes, int n_in,
                              void* d_out, int out_size, void* d_ws, size_t ws_size,
                              hipStream_t stream) {
    (void)in_sizes; (void)n_in; (void)out_size; (void)ws_size;
    const float* x    = (const float*)d_in[0];
    const int*   mask = (const int*)d_in[1];
    const float* Wq   = (const float*)d_in[2];
    const float* bq   = (const float*)d_in[3];
    const float* Wk   = (const float*)d_in[4];
    const float* bk   = (const float*)d_in[5];
    const float* Wv   = (const float*)d_in[6];
    const float* bv   = (const float*)d_in[7];
    float* out = (float*)d_out;

    const size_t MB = (size_t)1 << 20;
    char* base = (char*)d_ws;
    unsigned short* qb  = (unsigned short*)(base);            //  0..8 MB
    unsigned short* kb  = (unsigned short*)(base + 8 * MB);   //  8..16
    unsigned short* vtb = (unsigned short*)(base + 16 * MB);  // 16..24
    unsigned char*  mk  = (unsigned char*)(base + 24 * MB);   // 24..32
    // 32..46 MB: xb/wtb live during prep+qkv only; then O0 (bf16, 8 MB) + lws
    unsigned short* xb  = (unsigned short*)(base + 32 * MB);  // 32..40
    unsigned short* wtb = (unsigned short*)(base + 40 * MB);  // 40..46
    unsigned short* O0  = (unsigned short*)(base + 32 * MB);  // 32..40 (after qkv)
    float* lws = (float*)(base + 40 * MB);                    // 40..40.5

    prep<<<4864, 256, 0, stream>>>(x, xb, mask, mk, Wq, Wk, Wv, wtb);
    qkv_gemm<<<dim3(24, 32), 256, 0, stream>>>(xb, wtb, bq, bk, bv, qb, kb, vtb);
    attn_mfma<<<dim3(16, 16, 4), 256, 0, stream>>>(qb, kb, vtb, mk, O0, out, lws);
    combine<<<4096, 256, 0, stream>>>(O0, out, lws);
}

// Round 8
// 261.706 us; speedup vs baseline: 1.1355x; 1.1355x over previous
//
#include <hip/hip_runtime.h>
#include <cstdint>
#include <cstddef>

static constexpr int B_ = 2, S_ = 2048, D_ = 1024, H_ = 16, HD_ = 64;

typedef float f32x4 __attribute__((ext_vector_type(4)));
typedef short bf16x8 __attribute__((ext_vector_type(8)));

__device__ __forceinline__ unsigned short f2bf(float f) {
    union { float f; unsigned int u; } v; v.f = f;
    unsigned int r = v.u + 0x7FFFu + ((v.u >> 16) & 1u);   // RNE
    return (unsigned short)(r >> 16);
}
__device__ __forceinline__ float bf2f(unsigned short h) {
    union { unsigned int u; float f; } v; v.u = ((unsigned int)h) << 16;
    return v.f;
}

__device__ __forceinline__ unsigned pack2bf(float a, float b) {
#if __has_builtin(__builtin_amdgcn_cvt_pk_bf16_f32)
    auto p = __builtin_amdgcn_cvt_pk_bf16_f32(a, b);
    unsigned u; __builtin_memcpy(&u, &p, 4);
    return u;
#else
    return (unsigned)f2bf(a) | ((unsigned)f2bf(b) << 16);
#endif
}

// byte r of u -> float (0.0 or 1.0 for our inverted mask bytes)
__device__ __forceinline__ float ubyte2f(unsigned u, int r) {
#if __has_builtin(__builtin_amdgcn_cvt_f32_ubyte0)
    switch (r) {
        case 0: return __builtin_amdgcn_cvt_f32_ubyte0(u);
        case 1: return __builtin_amdgcn_cvt_f32_ubyte1(u);
        case 2: return __builtin_amdgcn_cvt_f32_ubyte2(u);
        default: return __builtin_amdgcn_cvt_f32_ubyte3(u);
    }
#else
    return (float)((u >> (8 * r)) & 0xFFu);
#endif
}

// async global->LDS, 16B per lane. LDS dest = wave-uniform base + lane*16.
__device__ __forceinline__ void gload_lds16(const void* g, void* l) {
    __builtin_amdgcn_global_load_lds(
        (const __attribute__((address_space(1))) void*)g,
        (__attribute__((address_space(3))) void*)l, 16, 0, 0);
}

// ---------------------------------------------------------------------------
// Fused prep: [0,2048) cast x->bf16 | [2048,4096) mask int32 -> INVERTED u8
// (1 = keep, 0 = masked) | [4096,4864) W transpose+cast.
// ---------------------------------------------------------------------------
__global__ __launch_bounds__(256)
void prep(const float* __restrict__ x, unsigned short* __restrict__ xo,
          const int* __restrict__ m, unsigned char* __restrict__ mo,
          const float* __restrict__ Wq, const float* __restrict__ Wk,
          const float* __restrict__ Wv, unsigned short* __restrict__ wt) {
    __shared__ unsigned short Ts[64][72];
    const int bid = blockIdx.x, t = threadIdx.x;
    if (bid < 2048) {
        size_t i = ((size_t)bid * 256 + t) * 8;
        float4 a = *(const float4*)(x + i);
        float4 c = *(const float4*)(x + i + 4);
        uint4 r;
        r.x = pack2bf(a.x, a.y); r.y = pack2bf(a.z, a.w);
        r.z = pack2bf(c.x, c.y); r.w = pack2bf(c.z, c.w);
        *(uint4*)(xo + i) = r;
    } else if (bid < 4096) {
        size_t i = ((size_t)(bid - 2048) * 256 + t) * 16;
        uint4 r;
        unsigned w[4];
        #pragma unroll
        for (int g = 0; g < 4; ++g) {
            int4 v = *(const int4*)(m + i + g * 4);
            w[g] = (v.x ? 0u : 1u) | (v.y ? 0u : 1u << 8) |
                   (v.z ? 0u : 1u << 16) | (v.w ? 0u : 1u << 24);
        }
        r.x = w[0]; r.y = w[1]; r.z = w[2]; r.w = w[3];
        *(uint4*)(mo + i) = r;
    } else {
        const int tid = bid - 4096;            // 0..767
        const int mat = tid >> 8, tile = tid & 255;
        const float* __restrict__ W = (mat == 0) ? Wq : (mat == 1) ? Wk : Wv;
        unsigned short* __restrict__ o = wt + (size_t)mat * D_ * D_;
        const int n0 = (tile & 15) * 64, k0 = (tile >> 4) * 64;
        {
            const int nl = t & 63, kb = t >> 6;
            #pragma unroll
            for (int i = 0; i < 16; ++i) {
                int k = kb + i * 4;
                Ts[nl][k] = f2bf(W[(size_t)(k0 + k) * D_ + n0 + nl]);
            }
        }
        __syncthreads();
        {
            const int kl = t & 63, nb = t >> 6;
            #pragma unroll
            for (int i = 0; i < 16; ++i) {
                int n = nb + i * 4;
                o[(size_t)(n0 + n) * D_ + k0 + kl] = Ts[n][kl];
            }
        }
    }
}

// ---------------------------------------------------------------------------
// QKV GEMM, bf16 MFMA 16x16x32. 128x128 tile, BK=32, single-barrier dbuf DMA,
// XOR-swizzled LDS (verified passing rounds 5-7).
// mat0 (Q): scaled by 0.125*log2(e). mat2 (V): stored transposed vt[bh][d][s].
// ---------------------------------------------------------------------------
__global__ __launch_bounds__(256)
void qkv_gemm(const unsigned short* __restrict__ xb, const unsigned short* __restrict__ wt,
              const float* __restrict__ bq, const float* __restrict__ bk,
              const float* __restrict__ bv,
              unsigned short* __restrict__ qo, unsigned short* __restrict__ ko,
              unsigned short* __restrict__ vto) {
    const int bx = blockIdx.x;
    const int by = blockIdx.y;
    const int mat = bx >> 3;
    const int ncol0 = (bx & 7) * 128;
    const float* __restrict__ bias = (mat == 0) ? bq : (mat == 1) ? bk : bv;
    const unsigned short* __restrict__ Wm = wt + (size_t)mat * D_ * D_;

    __shared__ unsigned short As[2][128 * 32];
    __shared__ unsigned short Bs[2][128 * 32];

    const int t = threadIdx.x;
    const int w = t >> 6, lane = t & 63;
    const int l15 = lane & 15, quad = lane >> 4;
    const int mw = (w >> 1) * 64, nw = (w & 1) * 64;
    const int rowBase = by * 128;

    const int r16 = lane >> 2;
    const int sslot = lane & 3;
    const int sg = (sslot ^ ((r16 >> 1) & 3)) * 8;
    const int rcol = (quad ^ ((l15 >> 1) & 3)) * 8;

    f32x4 acc[4][4] = {};

    #pragma unroll
    for (int j = 0; j < 2; ++j) {
        const int r0 = w * 32 + j * 16;
        gload_lds16(xb + (size_t)(rowBase + r0 + r16) * D_ + sg, &As[0][r0 * 32]);
        gload_lds16(Wm + (size_t)(ncol0 + r0 + r16) * D_ + sg, &Bs[0][r0 * 32]);
    }

    for (int it = 0; it < 32; ++it) {
        const int cur = it & 1;
        __syncthreads();
        if (it + 1 < 32) {
            const int ktn = (it + 1) * 32;
            #pragma unroll
            for (int j = 0; j < 2; ++j) {
                const int r0 = w * 32 + j * 16;
                gload_lds16(xb + (size_t)(rowBase + r0 + r16) * D_ + ktn + sg,
                            &As[cur ^ 1][r0 * 32]);
                gload_lds16(Wm + (size_t)(ncol0 + r0 + r16) * D_ + ktn + sg,
                            &Bs[cur ^ 1][r0 * 32]);
            }
        }

        bf16x8 a[4], b[4];
        #pragma unroll
        for (int i = 0; i < 4; ++i)
            a[i] = *(const bf16x8*)&As[cur][(mw + i * 16 + l15) * 32 + rcol];
        #pragma unroll
        for (int j = 0; j < 4; ++j)
            b[j] = *(const bf16x8*)&Bs[cur][(nw + j * 16 + l15) * 32 + rcol];
        #pragma unroll
        for (int i = 0; i < 4; ++i)
            #pragma unroll
            for (int j = 0; j < 4; ++j)
                acc[i][j] = __builtin_amdgcn_mfma_f32_16x16x32_bf16(a[i], b[j], acc[i][j], 0, 0, 0);
    }

    if (mat < 2) {
        unsigned short* __restrict__ O = (mat == 0) ? qo : ko;
        const float osc = (mat == 0) ? 0.18033688011112443f : 1.0f;  // 0.125*log2(e)
        #pragma unroll
        for (int j = 0; j < 4; ++j) {
            const int col = ncol0 + nw + j * 16 + l15;
            const float bb = bias[col];
            #pragma unroll
            for (int i = 0; i < 4; ++i)
                #pragma unroll
                for (int r = 0; r < 4; ++r) {
                    const int m = rowBase + mw + i * 16 + quad * 4 + r;
                    O[(size_t)m * D_ + col] = f2bf((acc[i][j][r] + bb) * osc);
                }
        }
    } else {
        #pragma unroll
        for (int j = 0; j < 4; ++j) {
            const int col = ncol0 + nw + j * 16 + l15;
            const float bb = bias[col];
            const int hh = col >> 6, hd = col & 63;
            #pragma unroll
            for (int i = 0; i < 4; ++i) {
                const int m0 = rowBase + mw + i * 16 + quad * 4;
                const int bg = m0 >> 11, s0 = m0 & 2047;
                ushort4 pk;
                pk.x = f2bf(acc[i][j][0] + bb);
                pk.y = f2bf(acc[i][j][1] + bb);
                pk.z = f2bf(acc[i][j][2] + bb);
                pk.w = f2bf(acc[i][j][3] + bb);
                *(ushort4*)&vto[(((size_t)bg * H_ + hh) * HD_ + hd) * S_ + s0] = pk;
            }
        }
    }
}

// ---------------------------------------------------------------------------
// Flash attention, bf16 MFMA, S^T orientation, 2-way KV-split.
// Block = (qt, h, b*2+half); keys [half*1024, half*1024+1024), 16 tiles of 64.
// K AND V both staged via double-buffered LDS DMA, XOR-swizzled (granule ^
// row&7) — V from global regressed (R7: latency in MFMA chain + vmcnt FIFO
// draining the K prefetch). P: LDS [128][64] swizzled, elem (qr,k) at
// qr*64 + ((k>>3)^(qr&7))*8 + (k&7).
// Emits UNNORMALIZED partials: half0 -> bf16 O0 (ws), half1 -> fp32 d_out;
// row-sums -> lws. combine() normalizes.
// Masking: p = exp2(score * fm), fm = inverted mask byte -> masked p = 1
// (reference quirk). Q pre-scaled by 0.125*log2(e).
// LDS 48 KB -> 3 blocks/CU.
// ---------------------------------------------------------------------------
__global__ __launch_bounds__(256)
void attn_mfma(const unsigned short* __restrict__ qmat,
               const unsigned short* __restrict__ kmat,
               const unsigned short* __restrict__ vtg,
               const unsigned char* __restrict__ msk,
               unsigned short* __restrict__ O0, float* __restrict__ O1,
               float* __restrict__ lws) {
    const int qt = blockIdx.x, h = blockIdx.y;
    const int b = blockIdx.z >> 1, half = blockIdx.z & 1;
    const int t = threadIdx.x, w = t >> 6, lane = t & 63;
    const int l15 = lane & 15, quad = lane >> 4;
    const int q0 = qt * 128;
    const int kb0 = half * 1024;

    __shared__ unsigned short Ks[2][64 * 64];   // [key][d] swizzled
    __shared__ unsigned short Vs[2][64 * 64];   // [d][key] swizzled
    __shared__ unsigned short Ps[128 * 64];     // [qrow][key] swizzled

    const size_t bh = (size_t)b * S_ * D_ + (size_t)h * HD_;
    const unsigned short* __restrict__ qp = qmat + bh;
    const unsigned short* __restrict__ kp = kmat + bh;
    const unsigned short* __restrict__ vp = vtg + ((size_t)b * H_ + h) * HD_ * S_;
    const unsigned char* __restrict__ mb = msk + (size_t)b * S_ * S_;

    const int rs = lane >> 3, sslot = lane & 7;
    const int sg = (sslot ^ rs) * 8;            // staged global granule (shorts)
    const int l7 = l15 & 7;

    // Q fragments in registers (loop-invariant)
    bf16x8 qfr[2][2];
    #pragma unroll
    for (int nt = 0; nt < 2; ++nt)
        #pragma unroll
        for (int kst = 0; kst < 2; ++kst)
            qfr[nt][kst] = *(const bf16x8*)(qp +
                (size_t)(q0 + w * 32 + nt * 16 + l15) * D_ + kst * 32 + quad * 8);

    f32x4 accO[2][4] = {};
    f32x4 lsA[2] = {};
    bf16x8 ones;
    #pragma unroll
    for (int i = 0; i < 8; ++i) ones[i] = (short)0x3F80;   // bf16 1.0

    // prologue: stage tile 0 (K and V) into buffer 0
    #pragma unroll
    for (int j = 0; j < 2; ++j) {
        const int rb = w * 16 + j * 8;
        gload_lds16(kp + (size_t)(kb0 + rb + rs) * D_ + sg, &Ks[0][rb * 64]);
        gload_lds16(vp + (size_t)(rb + rs) * S_ + kb0 + sg, &Vs[0][rb * 64]);
    }

    for (int it = 0; it < 16; ++it) {
        const int cur = it & 1;
        const int kt = kb0 + it * 64;
        __syncthreads();   // buf cur DMA drained; readers of buf cur^1 done

        // 1) mask loads first (oldest in vmcnt FIFO: consuming them doesn't
        //    drain the prefetch DMA issued after)
        unsigned mu[2][4];
        #pragma unroll
        for (int nt = 0; nt < 2; ++nt) {
            const int qr = w * 32 + nt * 16 + l15;
            const unsigned char* __restrict__ mrow = mb + (size_t)(q0 + qr) * S_ + kt;
            #pragma unroll
            for (int mt = 0; mt < 4; ++mt)
                mu[nt][mt] = *(const unsigned*)(mrow + mt * 16 + quad * 4);
        }

        // 2) prefetch next K+V tile into the other buffer
        if (it + 1 < 16) {
            const int ktn = kt + 64;
            #pragma unroll
            for (int j = 0; j < 2; ++j) {
                const int rb = w * 16 + j * 8;
                gload_lds16(kp + (size_t)(ktn + rb + rs) * D_ + sg, &Ks[cur ^ 1][rb * 64]);
                gload_lds16(vp + (size_t)(rb + rs) * S_ + ktn + sg, &Vs[cur ^ 1][rb * 64]);
            }
        }

        // 3) S^T = K·Q^T
        f32x4 sc[4][2] = {};
        #pragma unroll
        for (int kst = 0; kst < 2; ++kst) {
            bf16x8 kfr[4];
            #pragma unroll
            for (int mt = 0; mt < 4; ++mt) {
                const int R = mt * 16 + l15;
                kfr[mt] = *(const bf16x8*)&Ks[cur][R * 64 + ((kst * 4 + quad) ^ l7) * 8];
            }
            #pragma unroll
            for (int mt = 0; mt < 4; ++mt)
                #pragma unroll
                for (int nt = 0; nt < 2; ++nt)
                    sc[mt][nt] = __builtin_amdgcn_mfma_f32_16x16x32_bf16(kfr[mt], qfr[nt][kst], sc[mt][nt], 0, 0, 0);
        }

        // 4) p = exp2(s * fm); packed P^T store into swizzled Ps.
        //    k = mt*16 + quad*4 + r: granule mt*2+(quad>>1), intra-offset
        //    (quad&1)*4, granule swizzled by ^(qr&7)=l7.
        #pragma unroll
        for (int nt = 0; nt < 2; ++nt) {
            const int qr = w * 32 + nt * 16 + l15;
            #pragma unroll
            for (int mt = 0; mt < 4; ++mt) {
                float p[4];
                #pragma unroll
                for (int r = 0; r < 4; ++r) {
                    float fm = ubyte2f(mu[nt][mt], r);
                    p[r] = __builtin_amdgcn_exp2f(sc[mt][nt][r] * fm);
                }
                uint2 pk;
                pk.x = pack2bf(p[0], p[1]);
                pk.y = pack2bf(p[2], p[3]);
                const int gw = (mt * 2 + (quad >> 1)) ^ l7;
                *(uint2*)&Ps[qr * 64 + gw * 8 + (quad & 1) * 4] = pk;
            }
        }
        // Ps rows are wave-private (w*32 strip): no barrier needed.

        // 5) O += P·V (both operands from LDS), lsum += P·1
        #pragma unroll
        for (int kst = 0; kst < 2; ++kst) {
            bf16x8 vfr[4];
            #pragma unroll
            for (int dt = 0; dt < 4; ++dt) {
                const int R = dt * 16 + l15;
                vfr[dt] = *(const bf16x8*)&Vs[cur][R * 64 + ((kst * 4 + quad) ^ l7) * 8];
            }
            #pragma unroll
            for (int mt = 0; mt < 2; ++mt) {
                const int R = w * 32 + mt * 16 + l15;
                bf16x8 pfr = *(const bf16x8*)&Ps[R * 64 + ((kst * 4 + quad) ^ l7) * 8];
                #pragma unroll
                for (int dt = 0; dt < 4; ++dt)
                    accO[mt][dt] = __builtin_amdgcn_mfma_f32_16x16x32_bf16(pfr, vfr[dt], accO[mt][dt], 0, 0, 0);
                lsA[mt] = __builtin_amdgcn_mfma_f32_16x16x32_bf16(pfr, ones, lsA[mt], 0, 0, 0);
            }
        }
    }

    // store UNNORMALIZED partial O + l
    float* __restrict__ lp = lws + (((size_t)half * B_ + b) * H_ + h) * S_ + q0;
    if (half == 0) {
        unsigned short* __restrict__ ob = O0 + ((size_t)b * S_ + q0) * D_ + (size_t)h * HD_;
        #pragma unroll
        for (int mt = 0; mt < 2; ++mt)
            #pragma unroll
            for (int r = 0; r < 4; ++r) {
                const int qr = w * 32 + mt * 16 + quad * 4 + r;
                if (l15 == 0) lp[qr] = lsA[mt][r];
                #pragma unroll
                for (int dt = 0; dt < 4; ++dt)
                    ob[(size_t)qr * D_ + dt * 16 + l15] = f2bf(accO[mt][dt][r]);
            }
    } else {
        float* __restrict__ ob = O1 + ((size_t)b * S_ + q0) * D_ + (size_t)h * HD_;
        #pragma unroll
        for (int mt = 0; mt < 2; ++mt)
            #pragma unroll
            for (int r = 0; r < 4; ++r) {
                const int qr = w * 32 + mt * 16 + quad * 4 + r;
                if (l15 == 0) lp[qr] = lsA[mt][r];
                #pragma unroll
                for (int dt = 0; dt < 4; ++dt)
                    ob[(size_t)qr * D_ + dt * 16 + l15] = accO[mt][dt][r];
            }
    }
}

// ---------------------------------------------------------------------------
// combine: out = (bf2f(O0) + O1) / (l0 + l1).  O1 lives in d_out (in-place).
// ---------------------------------------------------------------------------
__global__ __launch_bounds__(256)
void combine(const unsigned short* __restrict__ O0, float* __restrict__ out,
             const float* __restrict__ lws) {
    const size_t i = ((size_t)blockIdx.x * 256 + threadIdx.x) * 4;
    const int sf = (int)(i >> 10);           // row in [0, B*S)
    const int b = sf >> 11, s = sf & 2047;
    const int h = ((int)i & 1023) >> 6;
    const float l0 = lws[(((size_t)0 * B_ + b) * H_ + h) * S_ + s];
    const float l1 = lws[(((size_t)1 * B_ + b) * H_ + h) * S_ + s];
    const float inv = 1.0f / (l0 + l1);
    ushort4 a = *(const ushort4*)(O0 + i);
    float4 c = *(const float4*)(out + i);
    float4 r;
    r.x = (bf2f(a.x) + c.x) * inv; r.y = (bf2f(a.y) + c.y) * inv;
    r.z = (bf2f(a.z) + c.z) * inv; r.w = (bf2f(a.w) + c.w) * inv;
    *(float4*)(out + i) = r;
}

extern "C" void kernel_launch(void* const* d_in, const int* in_sizes, int n_in,
                              void* d_out, int out_size, void* d_ws, size_t ws_size,
                              hipStream_t stream) {
    (void)in_sizes; (void)n_in; (void)out_size; (void)ws_size;
    const float* x    = (const float*)d_in[0];
    const int*   mask = (const int*)d_in[1];
    const float* Wq   = (const float*)d_in[2];
    const float* bq   = (const float*)d_in[3];
    const float* Wk   = (const float*)d_in[4];
    const float* bk   = (const float*)d_in[5];
    const float* Wv   = (const float*)d_in[6];
    const float* bv   = (const float*)d_in[7];
    float* out = (float*)d_out;

    const size_t MB = (size_t)1 << 20;
    char* base = (char*)d_ws;
    unsigned short* qb  = (unsigned short*)(base);            //  0..8 MB
    unsigned short* kb  = (unsigned short*)(base + 8 * MB);   //  8..16
    unsigned short* vtb = (unsigned short*)(base + 16 * MB);  // 16..24
    unsigned char*  mk  = (unsigned char*)(base + 24 * MB);   // 24..32
    // 32..46 MB: xb/wtb live during prep+qkv only; then O0 (bf16, 8 MB) + lws
    unsigned short* xb  = (unsigned short*)(base + 32 * MB);  // 32..40
    unsigned short* wtb = (unsigned short*)(base + 40 * MB);  // 40..46
    unsigned short* O0  = (unsigned short*)(base + 32 * MB);  // 32..40 (after qkv)
    float* lws = (float*)(base + 40 * MB);                    // 40..40.5

    prep<<<4864, 256, 0, stream>>>(x, xb, mask, mk, Wq, Wk, Wv, wtb);
    qkv_gemm<<<dim3(24, 32), 256, 0, stream>>>(xb, wtb, bq, bk, bv, qb, kb, vtb);
    attn_mfma<<<dim3(16, 16, 4), 256, 0, stream>>>(qb, kb, vtb, mk, O0, out, lws);
    combine<<<4096, 256, 0, stream>>>(O0, out, lws);
}